// Round 2
// baseline (592.738 us; speedup 1.0000x reference)
//
#include <hip/hip_runtime.h>
#include <hip/hip_bf16.h>
#include <math.h>

typedef short bf16x8 __attribute__((ext_vector_type(8)));
typedef float f32x4 __attribute__((ext_vector_type(4)));

#define HEADS 16
#define HDIM 64
#define HID 1024
#define B_ 4
#define T_ 2048
#define BT_ (B_*T_)      /* 8192 */
#define N1 (7*HID)       /* 7168 */
#define K2 (5*HID)       /* 5120 */

__device__ __forceinline__ float bf2f(unsigned short u) {
  union { unsigned int i; float f; } c; c.i = ((unsigned int)u) << 16; return c.f;
}
__device__ __forceinline__ unsigned short f2bf(float f) {
  __hip_bfloat16 h = __float2bfloat16(f);
  return __builtin_bit_cast(unsigned short, h);
}

typedef __attribute__((address_space(1))) const unsigned int gu32;
typedef __attribute__((address_space(3))) unsigned int lu32;
__device__ __forceinline__ void async16(const void* g, void* l) {
  __builtin_amdgcn_global_load_lds((gu32*)g, (lu32*)l, 16, 0, 0);
}

// ---------------- transpose + cast: in [R][C] f32 -> out [C][R] bf16 ----------------
__global__ __launch_bounds__(256) void tcast_kernel(const float* __restrict__ in,
                                                    unsigned short* __restrict__ out,
                                                    int R, int C) {
  __shared__ float tile[64][65];
  int tx = threadIdx.x & 63;
  int ty = threadIdx.x >> 6;
  long r0 = (long)blockIdx.y * 64;
  long c0 = (long)blockIdx.x * 64;
#pragma unroll
  for (int i = 0; i < 16; i++) {
    int r = ty + i * 4;
    tile[r][tx] = in[(r0 + r) * C + c0 + tx];
  }
  __syncthreads();
#pragma unroll
  for (int i = 0; i < 16; i++) {
    int rr = ty + i * 4;
    out[(c0 + rr) * R + r0 + tx] = f2bf(tile[tx][rr]);
  }
}

// ---------------- LayerNorm f32 -> bf16 ----------------
__global__ __launch_bounds__(256) void ln_kernel(const float* __restrict__ x,
                                                 const float* __restrict__ g,
                                                 const float* __restrict__ b,
                                                 unsigned short* __restrict__ xn) {
  int row = blockIdx.x, tid = threadIdx.x;
  float4 v = reinterpret_cast<const float4*>(x + (long)row * HID)[tid];
  float s = v.x + v.y + v.z + v.w;
  float sq = v.x * v.x + v.y * v.y + v.z * v.z + v.w * v.w;
#pragma unroll
  for (int off = 32; off > 0; off >>= 1) { s += __shfl_down(s, off); sq += __shfl_down(sq, off); }
  __shared__ float red[8];
  int wid = tid >> 6, lane = tid & 63;
  if (lane == 0) { red[wid] = s; red[4 + wid] = sq; }
  __syncthreads();
  if (tid == 0) {
    red[0] = red[0] + red[1] + red[2] + red[3];
    red[4] = red[4] + red[5] + red[6] + red[7];
  }
  __syncthreads();
  float mean = red[0] * (1.f / HID);
  float var  = red[4] * (1.f / HID) - mean * mean;
  float rstd = rsqrtf(var + 1e-5f);
  float4 gv = reinterpret_cast<const float4*>(g)[tid];
  float4 bv = reinterpret_cast<const float4*>(b)[tid];
  ushort4 o;
  o.x = f2bf((v.x - mean) * rstd * gv.x + bv.x);
  o.y = f2bf((v.y - mean) * rstd * gv.y + bv.y);
  o.z = f2bf((v.z - mean) * rstd * gv.z + bv.z);
  o.w = f2bf((v.w - mean) * rstd * gv.w + bv.w);
  reinterpret_cast<ushort4*>(xn + (long)row * HID)[tid] = o;
}

// ---------------- GEMM1 with fused rotary / V-transpose / GELU epilogue ----------------
// A [8192,1024] bf16, BT = w_inT [7168,1024] bf16.
// Output routing by column region: q,k -> rotary -> q_r/k_r [bh][t][64];
// v -> transpose -> v_t [bh][64][T]; p -> gelu -> C5 cols [1024,5120).
__global__ __launch_bounds__(256) void gemm1_fused(const unsigned short* __restrict__ A,
                                                   const unsigned short* __restrict__ BT,
                                                   unsigned short* __restrict__ q_r,
                                                   unsigned short* __restrict__ k_r,
                                                   unsigned short* __restrict__ v_t,
                                                   unsigned short* __restrict__ C5) {
  __shared__ unsigned short As[128 * 32];
  __shared__ unsigned short Bs[128 * 32];
  __shared__ unsigned short Vt[4][64 * 72];
  int tid = threadIdx.x, lane = tid & 63, wid = tid >> 6;
  long row0 = (long)blockIdx.y * 128;
  long col0 = (long)blockIdx.x * 128;
  f32x4 acc[4][4] = {};
  int srow = lane >> 2;
  int scol = (lane & 3) * 8;
  for (int k0 = 0; k0 < HID; k0 += 32) {
#pragma unroll
    for (int i = 0; i < 2; i++) {
      int c = wid * 2 + i;
      async16(A  + (row0 + c * 16 + srow) * (long)HID + k0 + scol, &As[c * 512]);
      async16(BT + (col0 + c * 16 + srow) * (long)HID + k0 + scol, &Bs[c * 512]);
    }
    __syncthreads();
    int wm = (wid & 1) * 64, wn = (wid >> 1) * 64;
    bf16x8 af[4], bfv[4];
#pragma unroll
    for (int m = 0; m < 4; m++)
      af[m] = *reinterpret_cast<const bf16x8*>(&As[(wm + m * 16 + (lane & 15)) * 32 + (lane >> 4) * 8]);
#pragma unroll
    for (int n = 0; n < 4; n++)
      bfv[n] = *reinterpret_cast<const bf16x8*>(&Bs[(wn + n * 16 + (lane & 15)) * 32 + (lane >> 4) * 8]);
#pragma unroll
    for (int m = 0; m < 4; m++)
#pragma unroll
      for (int n = 0; n < 4; n++)
        acc[m][n] = __builtin_amdgcn_mfma_f32_16x16x32_bf16(af[m], bfv[n], acc[m][n], 0, 0, 0);
    __syncthreads();
  }
  int wm = (wid & 1) * 64, wn = (wid >> 1) * 64;
  long row_base = row0 + wm;                 // 64-aligned
  int b = (int)(row_base >> 11);
  int t_base = (int)(row_base & 2047);
  int col_base = (int)col0 + wn;             // 64-aligned, one head / region per wave
  int region = col_base >> 10;               // 0=q 1=k 2=v 3..6=p
  int l15 = lane & 15, lq = lane >> 4;

  if (region <= 1) {
    // rotary: pair (d, d+32) = (acc[m][n][j], acc[m][n+2][j]), d = n*16+l15, n in {0,1}
    unsigned short* dst = (region == 0) ? q_r : k_r;
    int head = (col_base & 1023) >> 6;
    long obase = (long)(b * 16 + head) * T_ * 64;
    float fr[2];
    fr[0] = __expf(-(float)l15 * 0.28782313662425572f);          // 10000^(-d/32)
    fr[1] = __expf(-(float)(16 + l15) * 0.28782313662425572f);
#pragma unroll
    for (int m = 0; m < 4; m++) {
#pragma unroll
      for (int j = 0; j < 4; j++) {
        int t = t_base + m * 16 + lq * 4 + j;
#pragma unroll
        for (int n = 0; n < 2; n++) {
          float sn, cs;
          sincosf((float)t * fr[n], &sn, &cs);
          float xl = acc[m][n][j], xh = acc[m][n + 2][j];
          int d = n * 16 + l15;
          dst[obase + (long)t * 64 + d]      = f2bf(xl * cs - xh * sn);
          dst[obase + (long)t * 64 + d + 32] = f2bf(xl * sn + xh * cs);
        }
      }
    }
  } else if (region == 2) {
    // V: per-wave 64x64 transpose through LDS, store as [bh][d][T]
    int head = (col_base & 1023) >> 6;
    unsigned short* vt = &Vt[wid][0];
#pragma unroll
    for (int m = 0; m < 4; m++)
#pragma unroll
      for (int n = 0; n < 4; n++)
#pragma unroll
        for (int j = 0; j < 4; j++)
          vt[(n * 16 + l15) * 72 + m * 16 + lq * 4 + j] = f2bf(acc[m][n][j]);
    // wave-internal write->read; lockstep wave, compiler inserts lgkmcnt
    long obase = (long)(b * 16 + head) * 64 * T_;
#pragma unroll
    for (int i = 0; i < 8; i++) {
      int d = i * 8 + (lane >> 3);
      int tl = (lane & 7) * 8;
      bf16x8 v = *reinterpret_cast<const bf16x8*>(&vt[d * 72 + tl]);
      *reinterpret_cast<bf16x8*>(v_t + obase + (long)d * T_ + t_base + tl) = v;
    }
  } else {
    // P: exact-erf gelu into concat cols [1024, 5120)
    int colp = col_base - 3 * HID;
#pragma unroll
    for (int m = 0; m < 4; m++) {
#pragma unroll
      for (int j = 0; j < 4; j++) {
        long row = row_base + m * 16 + lq * 4 + j;
#pragma unroll
        for (int n = 0; n < 4; n++) {
          float a = acc[m][n][j];
          float ga = 0.5f * a * (1.f + erff(a * 0.70710678118f));
          C5[row * K2 + HID + colp + n * 16 + l15] = f2bf(ga);
        }
      }
    }
  }
}

// ---------------- GEMM2: C5 [8192,5120] @ w_outT [1024,5120] + bias -> f32 ----------------
__global__ __launch_bounds__(256) void gemm_bt(const unsigned short* __restrict__ A,
                                               const unsigned short* __restrict__ BT,
                                               float* __restrict__ Cout,
                                               const float* __restrict__ bias,
                                               int K, int lda, int ldb, int ldc) {
  __shared__ unsigned short As[128 * 32];
  __shared__ unsigned short Bs[128 * 32];
  int tid = threadIdx.x, lane = tid & 63, wid = tid >> 6;
  long row0 = (long)blockIdx.y * 128;
  long col0 = (long)blockIdx.x * 128;
  f32x4 acc[4][4] = {};
  int srow = lane >> 2;
  int scol = (lane & 3) * 8;
  for (int k0 = 0; k0 < K; k0 += 32) {
#pragma unroll
    for (int i = 0; i < 2; i++) {
      int c = wid * 2 + i;
      async16(A  + (row0 + c * 16 + srow) * (long)lda + k0 + scol, &As[c * 512]);
      async16(BT + (col0 + c * 16 + srow) * (long)ldb + k0 + scol, &Bs[c * 512]);
    }
    __syncthreads();
    int wm = (wid & 1) * 64, wn = (wid >> 1) * 64;
    bf16x8 af[4], bfv[4];
#pragma unroll
    for (int m = 0; m < 4; m++)
      af[m] = *reinterpret_cast<const bf16x8*>(&As[(wm + m * 16 + (lane & 15)) * 32 + (lane >> 4) * 8]);
#pragma unroll
    for (int n = 0; n < 4; n++)
      bfv[n] = *reinterpret_cast<const bf16x8*>(&Bs[(wn + n * 16 + (lane & 15)) * 32 + (lane >> 4) * 8]);
#pragma unroll
    for (int m = 0; m < 4; m++)
#pragma unroll
      for (int n = 0; n < 4; n++)
        acc[m][n] = __builtin_amdgcn_mfma_f32_16x16x32_bf16(af[m], bfv[n], acc[m][n], 0, 0, 0);
    __syncthreads();
  }
  int wm = (wid & 1) * 64, wn = (wid >> 1) * 64;
#pragma unroll
  for (int m = 0; m < 4; m++) {
#pragma unroll
    for (int n = 0; n < 4; n++) {
      long r = row0 + wm + m * 16 + (lane >> 4) * 4;
      long c = col0 + wn + n * 16 + (lane & 15);
#pragma unroll
      for (int j = 0; j < 4; j++)
        Cout[(r + j) * (long)ldc + c] = acc[m][n][j] + bias[c];
    }
  }
}

// ---------------- flash attention (non-causal), Qtile=128, KVtile=64 ----------------
__global__ __launch_bounds__(256) void attn_kernel(const unsigned short* __restrict__ q_r,
                                                   const unsigned short* __restrict__ k_r,
                                                   const unsigned short* __restrict__ v_t,
                                                   unsigned short* __restrict__ C5) {
  int qt = blockIdx.x;  // 0..15
  int bh = blockIdx.y;  // 0..63
  int b = bh >> 4, h = bh & 15;
  int tid = threadIdx.x, lane = tid & 63, wid = tid >> 6;
  __shared__ unsigned short Qs[128 * 64];
  __shared__ unsigned short Ks[64 * 64];
  __shared__ unsigned short Vts[64 * 64];
  __shared__ unsigned short Ps[4][32 * 72];
  const unsigned short* qbase = q_r + ((long)bh * T_ + qt * 128) * 64;
#pragma unroll
  for (int i = 0; i < 4; i++) {
    int c = wid * 4 + i;
    async16(qbase + c * 512 + lane * 8, &Qs[c * 512]);
  }
  f32x4 o_acc[2][4] = {};
  float m_run[2][4], l_run[2][4];
#pragma unroll
  for (int m = 0; m < 2; m++)
#pragma unroll
    for (int j = 0; j < 4; j++) { m_run[m][j] = -1e30f; l_run[m][j] = 0.f; }
  const unsigned short* kbase = k_r + (long)bh * T_ * 64;
  const unsigned short* vbase = v_t + (long)bh * 64 * T_;
  for (int kt = 0; kt < 32; kt++) {
#pragma unroll
    for (int i = 0; i < 2; i++) {
      int c = wid * 2 + i;
      async16(kbase + (long)kt * 64 * 64 + c * 512 + lane * 8, &Ks[c * 512]);
      async16(vbase + (long)(c * 8 + (lane >> 3)) * T_ + kt * 64 + (lane & 7) * 8, &Vts[c * 512]);
    }
    __syncthreads();
    // S = Q K^T
    f32x4 s[2][4] = {};
    bf16x8 aq[2][2], bk[4][2];
#pragma unroll
    for (int m = 0; m < 2; m++)
#pragma unroll
      for (int kk = 0; kk < 2; kk++)
        aq[m][kk] = *reinterpret_cast<const bf16x8*>(
            &Qs[(wid * 32 + m * 16 + (lane & 15)) * 64 + kk * 32 + (lane >> 4) * 8]);
#pragma unroll
    for (int n = 0; n < 4; n++)
#pragma unroll
      for (int kk = 0; kk < 2; kk++)
        bk[n][kk] = *reinterpret_cast<const bf16x8*>(
            &Ks[(n * 16 + (lane & 15)) * 64 + kk * 32 + (lane >> 4) * 8]);
#pragma unroll
    for (int m = 0; m < 2; m++)
#pragma unroll
      for (int n = 0; n < 4; n++)
#pragma unroll
        for (int kk = 0; kk < 2; kk++)
          s[m][n] = __builtin_amdgcn_mfma_f32_16x16x32_bf16(aq[m][kk], bk[n][kk], s[m][n], 0, 0, 0);
    // online softmax; row within frag = (lane>>4)*4+j, cols across n and lane&15
    unsigned short* Pw = &Ps[wid][0];
#pragma unroll
    for (int m = 0; m < 2; m++) {
      float pm[4][4];
      float mt[4];
#pragma unroll
      for (int j = 0; j < 4; j++) {
        float v0 = s[m][0][j] * 0.125f, v1 = s[m][1][j] * 0.125f;
        float v2 = s[m][2][j] * 0.125f, v3 = s[m][3][j] * 0.125f;
        s[m][0][j] = v0; s[m][1][j] = v1; s[m][2][j] = v2; s[m][3][j] = v3;
        float t0 = fmaxf(fmaxf(v0, v1), fmaxf(v2, v3));
        t0 = fmaxf(t0, __shfl_xor(t0, 1));
        t0 = fmaxf(t0, __shfl_xor(t0, 2));
        t0 = fmaxf(t0, __shfl_xor(t0, 4));
        t0 = fmaxf(t0, __shfl_xor(t0, 8));
        mt[j] = t0;
      }
#pragma unroll
      for (int j = 0; j < 4; j++) {
        float mn = fmaxf(m_run[m][j], mt[j]);
        float corr = __expf(m_run[m][j] - mn);
        m_run[m][j] = mn;
        float ps = 0.f;
#pragma unroll
        for (int n = 0; n < 4; n++) {
          float p = __expf(s[m][n][j] - mn);
          pm[n][j] = p;
          ps += p;
        }
        ps += __shfl_xor(ps, 1);
        ps += __shfl_xor(ps, 2);
        ps += __shfl_xor(ps, 4);
        ps += __shfl_xor(ps, 8);
        l_run[m][j] = l_run[m][j] * corr + ps;
#pragma unroll
        for (int n = 0; n < 4; n++) o_acc[m][n][j] *= corr;
      }
#pragma unroll
      for (int n = 0; n < 4; n++)
#pragma unroll
        for (int j = 0; j < 4; j++)
          Pw[(m * 16 + (lane >> 4) * 4 + j) * 72 + n * 16 + (lane & 15)] = f2bf(pm[n][j]);
    }
    __syncthreads();
    // O += P V
    bf16x8 ap[2][2], bv[4][2];
#pragma unroll
    for (int m = 0; m < 2; m++)
#pragma unroll
      for (int kk = 0; kk < 2; kk++)
        ap[m][kk] = *reinterpret_cast<const bf16x8*>(
            &Pw[(m * 16 + (lane & 15)) * 72 + kk * 32 + (lane >> 4) * 8]);
#pragma unroll
    for (int n = 0; n < 4; n++)
#pragma unroll
      for (int kk = 0; kk < 2; kk++)
        bv[n][kk] = *reinterpret_cast<const bf16x8*>(
            &Vts[(n * 16 + (lane & 15)) * 64 + kk * 32 + (lane >> 4) * 8]);
#pragma unroll
    for (int m = 0; m < 2; m++)
#pragma unroll
      for (int n = 0; n < 4; n++)
#pragma unroll
        for (int kk = 0; kk < 2; kk++)
          o_acc[m][n] = __builtin_amdgcn_mfma_f32_16x16x32_bf16(ap[m][kk], bv[n][kk], o_acc[m][n], 0, 0, 0);
    __syncthreads();
  }
#pragma unroll
  for (int m = 0; m < 2; m++)
#pragma unroll
    for (int n = 0; n < 4; n++)
#pragma unroll
      for (int j = 0; j < 4; j++) {
        int tl = qt * 128 + wid * 32 + m * 16 + (lane >> 4) * 4 + j;
        long row = (long)b * T_ + tl;
        int col = h * 64 + n * 16 + (lane & 15);
        C5[row * K2 + col] = f2bf(o_acc[m][n][j] / l_run[m][j]);
      }
}

extern "C" void kernel_launch(void* const* d_in, const int* in_sizes, int n_in,
                              void* d_out, int out_size, void* d_ws, size_t ws_size,
                              hipStream_t stream) {
  const float* x     = (const float*)d_in[0];
  const float* g     = (const float*)d_in[1];
  const float* be    = (const float*)d_in[2];
  const float* w_in  = (const float*)d_in[3];
  const float* w_out = (const float*)d_in[4];
  const float* b_out = (const float*)d_in[5];
  float* out = (float*)d_out;

  char* ws = (char*)d_ws;
  size_t off = 0;
  auto alloc = [&](size_t bytes) {
    void* p = ws + off;
    off += (bytes + 255) & ~(size_t)255;
    return p;
  };
  // total: 16.8+14.7+10.5+16.8*3+83.9 = ~176.2 MB
  unsigned short* xn     = (unsigned short*)alloc((size_t)BT_ * HID * 2);
  unsigned short* w_inT  = (unsigned short*)alloc((size_t)N1 * HID * 2);
  unsigned short* w_outT = (unsigned short*)alloc((size_t)HID * K2 * 2);
  unsigned short* q_rb   = (unsigned short*)alloc((size_t)BT_ * HID * 2);
  unsigned short* k_rb   = (unsigned short*)alloc((size_t)BT_ * HID * 2);
  unsigned short* v_tb   = (unsigned short*)alloc((size_t)BT_ * HID * 2);
  unsigned short* C5     = (unsigned short*)alloc((size_t)BT_ * K2 * 2);

  // weight transposes + casts
  tcast_kernel<<<dim3(N1 / 64, HID / 64), 256, 0, stream>>>(w_in, w_inT, HID, N1);
  tcast_kernel<<<dim3(HID / 64, K2 / 64), 256, 0, stream>>>(w_out, w_outT, K2, HID);
  // layernorm
  ln_kernel<<<BT_, 256, 0, stream>>>(x, g, be, xn);
  // qkvp = xn @ w_in with fused rotary/V-transpose/gelu epilogue
  gemm1_fused<<<dim3(N1 / 128, BT_ / 128), 256, 0, stream>>>(xn, w_inT, q_rb, k_rb, v_tb, C5);
  // attention -> concat cols [0, 1024)
  attn_kernel<<<dim3(T_ / 128, 64), 256, 0, stream>>>(q_rb, k_rb, v_tb, C5);
  // out = concat @ w_out + b_out
  gemm_bt<<<dim3(HID / 128, BT_ / 128), 256, 0, stream>>>(C5, w_outT, out, b_out,
                                                          K2, K2, K2, HID);
}